// Round 1
// baseline (277.721 us; speedup 1.0000x reference)
//
#include <hip/hip_runtime.h>
#include <hip/hip_bf16.h>
#include <cstdint>
#include <cstddef>

// Problem constants (L=256, C=20, LC=5120, BATCH=1024)
#define LCN 5120
#define BN  1024
#define CN  20

typedef __attribute__((ext_vector_type(4))) float  floatx4;
typedef __attribute__((ext_vector_type(8))) short  shortx8;
typedef __attribute__((ext_vector_type(4))) unsigned short ushortx4;

static __device__ __forceinline__ unsigned short f2bf(float f) {
    __hip_bfloat16 h = __float2bfloat16(f);
    return *reinterpret_cast<unsigned short*>(&h);
}

static __device__ __forceinline__ void gload_lds16(const void* g, void* l) {
    __builtin_amdgcn_global_load_lds(
        (const __attribute__((address_space(1))) void*)g,
        (__attribute__((address_space(3))) void*)l,
        16, 0, 0);
}

// ---------------------------------------------------------------------------
// Pass 1a: Tt[i*5120 + j] = bf16(theta[j*5120 + i]) if l(i) > l(j) else 0
// grid (5120/64, 5120/32), block 512. Reads coalesced (64 consecutive i per
// lane group); writes 8B/lane scattered across rows -> L2 merges (32 j's of a
// row-line come from the same block).
// ---------------------------------------------------------------------------
__global__ void k_theta(const float* __restrict__ th, unsigned short* __restrict__ Tt) {
    const int i  = blockIdx.x * 64 + (threadIdx.x & 63);
    const int jc = (threadIdx.x >> 6) << 2;            // 0,4,..,28
    const int j0 = blockIdx.y * 32 + jc;
    const int li = i / CN;
    ushortx4 o;
#pragma unroll
    for (int t = 0; t < 4; ++t) {
        const int j = j0 + t;
        const float v = th[(size_t)j * LCN + i];
        o[t] = (li > j / CN) ? f2bf(v) : (unsigned short)0;
    }
    *reinterpret_cast<ushortx4*>(Tt + (size_t)i * LCN + j0) = o;
}

// ---------------------------------------------------------------------------
// Pass 1b: x fp32 -> bf16.  grid 5120, block 256 (exactly covers 1024*5120/4)
// ---------------------------------------------------------------------------
__global__ void k_x(const float* __restrict__ x, unsigned short* __restrict__ xb) {
    const size_t idx = (size_t)blockIdx.x * 256 + threadIdx.x;  // float4 index
    const floatx4 v = reinterpret_cast<const floatx4*>(x)[idx];
    ushortx4 o;
#pragma unroll
    for (int t = 0; t < 4; ++t) o[t] = f2bf(v[t]);
    reinterpret_cast<ushortx4*>(xb)[idx] = o;
}

// ---------------------------------------------------------------------------
// Pass 1c: out[b] = theta_0 + sum_i theta_lc[i] * x[b,i]   (fp32, exact)
// grid 1024, block 256
// ---------------------------------------------------------------------------
__global__ void k_init(const float* __restrict__ x, const float* __restrict__ th0,
                       const float* __restrict__ thlc, float* __restrict__ out) {
    const int b = blockIdx.x;
    const int tid = threadIdx.x;
    const floatx4* xr = reinterpret_cast<const floatx4*>(x + (size_t)b * LCN);
    const floatx4* tr = reinterpret_cast<const floatx4*>(thlc);
    float s = 0.0f;
    for (int k = tid; k < LCN / 4; k += 256) {
        const floatx4 a = xr[k], t = tr[k];
        s += a[0] * t[0] + a[1] * t[1] + a[2] * t[2] + a[3] * t[3];
    }
#pragma unroll
    for (int off = 32; off > 0; off >>= 1) s += __shfl_down(s, off, 64);
    __shared__ float ws4[4];
    if ((tid & 63) == 0) ws4[tid >> 6] = s;
    __syncthreads();
    if (tid == 0) out[b] = th0[0] + ws4[0] + ws4[1] + ws4[2] + ws4[3];
}

// ---------------------------------------------------------------------------
// Pass 2: masked-GEMM + fused dot-reduce.
//   blockIdx.x -> (n, c): N-tile n (128 cols of i), K-chunk c (512 of j)
//   blockIdx.y -> M-tile (128 rows of b)
//   Y_partial[b,i] = sum_{k in chunk} Xb[b,k] * Tt[i,k]  (Tt zero where masked)
//   out[b] += sum_i Y_partial[b,i] * Xf[b,i]
// m97 structure: BK=32, global_load_lds width=16, 4 waves x (4x4) 16x16x32 MFMA
// ---------------------------------------------------------------------------
__global__ __launch_bounds__(256) void k_quad(
    const unsigned short* __restrict__ Xb,   // [1024][5120] bf16
    const unsigned short* __restrict__ Tt,   // [5120][5120] bf16, row i over j
    const float*          __restrict__ Xf,   // [1024][5120] fp32
    float*                __restrict__ out)  // [1024]
{
    __shared__ unsigned short As[128 * 32];   // A tile: [row b][32 k]
    __shared__ unsigned short Bs[128 * 32];   // B tile: [row i][32 k]
    __shared__ float partial[128];

    const int tid  = threadIdx.x;
    const int lane = tid & 63;
    const int w    = tid >> 6;        // wave 0..3
    const int wm   = w & 1;           // M half
    const int wn   = w >> 1;          // N half
    const int lrow = lane & 15;
    const int kq   = lane >> 4;       // 0..3

    // map blockIdx.x -> (n, c); chunks(n) = ceil(20*floor((128n+127)/20)/512)
    int q = blockIdx.x, n = 0, c = 0;
    for (int t = 0; t < 40; ++t) {
        const int lmax = (128 * t + 127) / CN;
        const int ch   = (CN * lmax + 511) / 512;
        if (q < ch) { n = t; c = q; break; }
        q -= ch;
    }
    const int b0 = blockIdx.y * 128;
    const int n0 = n * 128;
    const int k0 = c * 512;

    if (tid < 128) partial[tid] = 0.0f;

    floatx4 acc[4][4];
#pragma unroll
    for (int mt = 0; mt < 4; ++mt)
#pragma unroll
        for (int nt = 0; nt < 4; ++nt) acc[mt][nt] = (floatx4)0.0f;

    for (int kk = 0; kk < 16; ++kk) {
        const int kc = k0 + kk * 32;
        // stage A and B tiles: 8 KB each; 512 x 16B segments / tile;
        // seg s = t*256 + tid -> LDS byte s*16 = row (s>>2) * 64 + (s&3)*16
#pragma unroll
        for (int t = 0; t < 2; ++t) {
            const int s   = t * 256 + tid;
            const int row = s >> 2;
            const int seg = s & 3;
            char* la = (char*)As + (size_t)(t * 256 + w * 64) * 16;  // wave-uniform
            char* lb = (char*)Bs + (size_t)(t * 256 + w * 64) * 16;
            gload_lds16(Xb + (size_t)(b0 + row) * LCN + kc + seg * 8, la);
            gload_lds16(Tt + (size_t)(n0 + row) * LCN + kc + seg * 8, lb);
        }
        __syncthreads();

        shortx8 af[4], bf[4];
#pragma unroll
        for (int mt = 0; mt < 4; ++mt)
            af[mt] = *reinterpret_cast<const shortx8*>(As + (wm * 64 + mt * 16 + lrow) * 32 + kq * 8);
#pragma unroll
        for (int nt = 0; nt < 4; ++nt)
            bf[nt] = *reinterpret_cast<const shortx8*>(Bs + (wn * 64 + nt * 16 + lrow) * 32 + kq * 8);
#pragma unroll
        for (int mt = 0; mt < 4; ++mt)
#pragma unroll
            for (int nt = 0; nt < 4; ++nt)
                acc[mt][nt] = __builtin_amdgcn_mfma_f32_16x16x32_bf16(af[mt], bf[nt], acc[mt][nt], 0, 0, 0);
        __syncthreads();
    }

    // Epilogue: C/D layout col = lane&15 (i), row = (lane>>4)*4 + reg (b)
#pragma unroll
    for (int mt = 0; mt < 4; ++mt) {
#pragma unroll
        for (int r = 0; r < 4; ++r) {
            const int b = b0 + wm * 64 + mt * 16 + kq * 4 + r;
            float s = 0.0f;
#pragma unroll
            for (int nt = 0; nt < 4; ++nt) {
                const int i = n0 + wn * 64 + nt * 16 + lrow;
                s += acc[mt][nt][r] * Xf[(size_t)b * LCN + i];
            }
            s += __shfl_xor(s, 1, 64);
            s += __shfl_xor(s, 2, 64);
            s += __shfl_xor(s, 4, 64);
            s += __shfl_xor(s, 8, 64);
            if (lrow == 0) atomicAdd(&partial[b - b0], s);
        }
    }
    __syncthreads();
    if (tid < 128) atomicAdd(&out[b0 + tid], partial[tid]);
}

// ---------------------------------------------------------------------------
extern "C" void kernel_launch(void* const* d_in, const int* in_sizes, int n_in,
                              void* d_out, int out_size, void* d_ws, size_t ws_size,
                              hipStream_t stream) {
    const float* x      = (const float*)d_in[0];  // [1024, 5120]
    const float* th0    = (const float*)d_in[1];  // [1]
    const float* thlc   = (const float*)d_in[2];  // [5120]
    const float* thlclc = (const float*)d_in[3];  // [5120, 5120]
    float* out = (float*)d_out;                   // [1024]

    // ws layout: Tt (bf16 5120x5120 = 52.4 MB) | Xb (bf16 1024x5120 = 10.5 MB)
    // total 62,914,560 bytes required.
    unsigned short* Tt = (unsigned short*)d_ws;
    unsigned short* Xb = (unsigned short*)((char*)d_ws + (size_t)LCN * LCN * 2);

    k_theta<<<dim3(LCN / 64, LCN / 32), 512, 0, stream>>>(thlclc, Tt);
    k_x<<<dim3((BN * LCN / 4) / 256), 256, 0, stream>>>(x, Xb);
    k_init<<<dim3(BN), 256, 0, stream>>>(x, th0, thlc, out);

    int tot = 0;
    for (int t = 0; t < 40; ++t) {
        const int lmax = (128 * t + 127) / CN;
        tot += (CN * lmax + 511) / 512;
    }
    k_quad<<<dim3(tot, BN / 128), 256, 0, stream>>>(Xb, Tt, x, out);
}

// Round 2
// 233.719 us; speedup vs baseline: 1.1883x; 1.1883x over previous
//
#include <hip/hip_runtime.h>
#include <hip/hip_bf16.h>
#include <cstdint>
#include <cstddef>

// Problem constants (L=256, C=20, LC=5120, BATCH=1024)
#define LCN 5120
#define BN  1024
#define CN  20
#define TP  65   // LDS transpose tile pad (odd -> conflict-light both phases)

typedef __attribute__((ext_vector_type(4))) float  floatx4;
typedef __attribute__((ext_vector_type(8))) short  shortx8;
typedef __attribute__((ext_vector_type(4))) unsigned short ushortx4;
typedef __attribute__((ext_vector_type(8))) unsigned short ushortx8;

static __device__ __forceinline__ unsigned short f2bf(float f) {
    __hip_bfloat16 h = __float2bfloat16(f);
    return *reinterpret_cast<unsigned short*>(&h);
}

static __device__ __forceinline__ void gload_lds16(const void* g, void* l) {
    __builtin_amdgcn_global_load_lds(
        (const __attribute__((address_space(1))) void*)g,
        (__attribute__((address_space(3))) void*)l,
        16, 0, 0);
}

// ---------------------------------------------------------------------------
// Pass 1a: masked bf16 transpose through LDS.
//   Tt[i*5120 + j] = bf16(theta[j*5120 + i]) if l(i) > l(j) else 0
// 64x64 tiles; reads coalesced (float4, 256B/row), writes coalesced
// (ushortx8, 128B/row). Blocks whose j-range lies beyond the chunk boundary
// k_quad reads for that row-tile are pruned entirely.
// ---------------------------------------------------------------------------
__global__ __launch_bounds__(256) void k_theta(const float* __restrict__ th,
                                               unsigned short* __restrict__ Tt) {
    const int i0 = blockIdx.x * 64;
    const int j0 = blockIdx.y * 64;
    // prune: k_quad reads rows of tile n = i0/128 only for j < ch*512
    const int lmax = (128 * (i0 / 128) + 127) / CN;
    const int ch   = (CN * lmax + 511) / 512;
    if (j0 >= ch * 512) return;

    __shared__ unsigned short Ts[64 * TP];   // [j_local][i_local]
    const int t = threadIdx.x;
    const int c = t & 15, r = t >> 4;        // read: 16 lanes x 16B per j-row
#pragma unroll
    for (int rr = 0; rr < 4; ++rr) {
        const int j  = j0 + rr * 16 + r;
        const int lj = j / CN;
        const floatx4 v = *reinterpret_cast<const floatx4*>(th + (size_t)j * LCN + i0 + c * 4);
#pragma unroll
        for (int e = 0; e < 4; ++e) {
            const int li = (i0 + c * 4 + e) / CN;
            Ts[(rr * 16 + r) * TP + c * 4 + e] = (li > lj) ? f2bf(v[e]) : (unsigned short)0;
        }
    }
    __syncthreads();
    const int c2 = t & 7, r2 = t >> 3;       // write: 8 lanes x 16B per i-row
#pragma unroll
    for (int ww = 0; ww < 2; ++ww) {
        const int il = ww * 32 + r2;
        ushortx8 o;
#pragma unroll
        for (int e = 0; e < 8; ++e) o[e] = Ts[(c2 * 8 + e) * TP + il];
        *reinterpret_cast<ushortx8*>(Tt + (size_t)(i0 + il) * LCN + j0 + c2 * 8) = o;
    }
}

// ---------------------------------------------------------------------------
// Pass 1b: fused  out[b] = theta_0 + sum_i theta_lc[i]*x[b,i]  (fp32, exact)
//          and    Xb[b,i] = bf16(x[b,i])
// grid 1024, block 256 — one block per batch row; single pass over x.
// ---------------------------------------------------------------------------
__global__ __launch_bounds__(256) void k_init(const float* __restrict__ x,
                                              const float* __restrict__ th0,
                                              const float* __restrict__ thlc,
                                              float* __restrict__ out,
                                              unsigned short* __restrict__ Xb) {
    const int b = blockIdx.x;
    const int tid = threadIdx.x;
    const floatx4* xr = reinterpret_cast<const floatx4*>(x + (size_t)b * LCN);
    const floatx4* tr = reinterpret_cast<const floatx4*>(thlc);
    ushortx4* xw = reinterpret_cast<ushortx4*>(Xb + (size_t)b * LCN);
    float s = 0.0f;
    for (int k = tid; k < LCN / 4; k += 256) {
        const floatx4 a = xr[k], t2 = tr[k];
        s += a[0] * t2[0] + a[1] * t2[1] + a[2] * t2[2] + a[3] * t2[3];
        ushortx4 o;
#pragma unroll
        for (int e = 0; e < 4; ++e) o[e] = f2bf(a[e]);
        xw[k] = o;
    }
#pragma unroll
    for (int off = 32; off > 0; off >>= 1) s += __shfl_down(s, off, 64);
    __shared__ float ws4[4];
    if ((tid & 63) == 0) ws4[tid >> 6] = s;
    __syncthreads();
    if (tid == 0) out[b] = th0[0] + ws4[0] + ws4[1] + ws4[2] + ws4[3];
}

// ---------------------------------------------------------------------------
// Pass 2: masked-GEMM + fused dot-reduce (m97 structure, 128x128 tile, BK=32).
// 1-D grid, XCD-pinned decode: assuming blocks round-robin XCDs by id%8,
// the 8 M-tiles of one K-chunk run consecutively on ONE XCD so the B tile is
// fetched to that XCD's L2 once instead of 8x.
//   id = 8*slot + xcd ; slot = 8*g + m ; chunk q = 8*g + xcd ; b0 = 128*m
// ---------------------------------------------------------------------------
__global__ __launch_bounds__(256) void k_quad(
    const unsigned short* __restrict__ Xb,   // [1024][5120] bf16
    const unsigned short* __restrict__ Tt,   // [5120][5120] bf16, row i over j
    float*                __restrict__ out,  // [1024]
    const int tot)                           // total chunk count (220)
{
    const int bid  = blockIdx.x;
    const int xcd  = bid & 7;
    const int slot = bid >> 3;
    const int m    = slot & 7;
    const int g    = slot >> 3;
    int q = g * 8 + xcd;
    if (q >= tot) return;

    __shared__ unsigned short As[128 * 32];   // A tile: [row b][32 k]
    __shared__ unsigned short Bs[128 * 32];   // B tile: [row i][32 k]
    __shared__ float partial[128];

    const int tid  = threadIdx.x;
    const int lane = tid & 63;
    const int w    = tid >> 6;        // wave 0..3
    const int wm   = w & 1;           // M half
    const int wn   = w >> 1;          // N half
    const int lrow = lane & 15;
    const int kq   = lane >> 4;       // 0..3

    // map chunk ordinal q -> (n, c); chunks(n) = ceil(20*floor((128n+127)/20)/512)
    int n = 0, c = 0;
    for (int t = 0; t < 40; ++t) {
        const int lmax = (128 * t + 127) / CN;
        const int chn  = (CN * lmax + 511) / 512;
        if (q < chn) { n = t; c = q; break; }
        q -= chn;
    }
    const int b0 = m * 128;
    const int n0 = n * 128;
    const int k0 = c * 512;

    if (tid < 128) partial[tid] = 0.0f;

    floatx4 acc[4][4];
#pragma unroll
    for (int mt = 0; mt < 4; ++mt)
#pragma unroll
        for (int nt = 0; nt < 4; ++nt) acc[mt][nt] = (floatx4)0.0f;

    for (int kk = 0; kk < 16; ++kk) {
        const int kc = k0 + kk * 32;
        // stage A and B tiles: 8 KB each; 512 x 16B segments per tile
#pragma unroll
        for (int t = 0; t < 2; ++t) {
            const int s   = t * 256 + tid;
            const int row = s >> 2;
            const int seg = s & 3;
            char* la = (char*)As + (size_t)(t * 256 + w * 64) * 16;  // wave-uniform
            char* lb = (char*)Bs + (size_t)(t * 256 + w * 64) * 16;
            gload_lds16(Xb + (size_t)(b0 + row) * LCN + kc + seg * 8, la);
            gload_lds16(Tt + (size_t)(n0 + row) * LCN + kc + seg * 8, lb);
        }
        __syncthreads();

        shortx8 af[4], bfr[4];
#pragma unroll
        for (int mt = 0; mt < 4; ++mt)
            af[mt] = *reinterpret_cast<const shortx8*>(As + (wm * 64 + mt * 16 + lrow) * 32 + kq * 8);
#pragma unroll
        for (int nt = 0; nt < 4; ++nt)
            bfr[nt] = *reinterpret_cast<const shortx8*>(Bs + (wn * 64 + nt * 16 + lrow) * 32 + kq * 8);
#pragma unroll
        for (int mt = 0; mt < 4; ++mt)
#pragma unroll
            for (int nt = 0; nt < 4; ++nt)
                acc[mt][nt] = __builtin_amdgcn_mfma_f32_16x16x32_bf16(af[mt], bfr[nt], acc[mt][nt], 0, 0, 0);
        __syncthreads();
    }

    // Epilogue: C/D layout col = lane&15 (i), row = (lane>>4)*4 + reg (b)
#pragma unroll
    for (int mt = 0; mt < 4; ++mt) {
#pragma unroll
        for (int r = 0; r < 4; ++r) {
            const int b = b0 + wm * 64 + mt * 16 + kq * 4 + r;
            float s = 0.0f;
#pragma unroll
            for (int nt = 0; nt < 4; ++nt) {
                const int i = n0 + wn * 64 + nt * 16 + lrow;
                const __hip_bfloat16 hv = *reinterpret_cast<const __hip_bfloat16*>(&Xb[(size_t)b * LCN + i]);
                s += acc[mt][nt][r] * __bfloat162float(hv);
            }
            s += __shfl_xor(s, 1, 64);
            s += __shfl_xor(s, 2, 64);
            s += __shfl_xor(s, 4, 64);
            s += __shfl_xor(s, 8, 64);
            if (lrow == 0) atomicAdd(&partial[b - b0], s);
        }
    }
    __syncthreads();
    if (tid < 128) atomicAdd(&out[b0 + tid], partial[tid]);
}

// ---------------------------------------------------------------------------
extern "C" void kernel_launch(void* const* d_in, const int* in_sizes, int n_in,
                              void* d_out, int out_size, void* d_ws, size_t ws_size,
                              hipStream_t stream) {
    const float* x      = (const float*)d_in[0];  // [1024, 5120]
    const float* th0    = (const float*)d_in[1];  // [1]
    const float* thlc   = (const float*)d_in[2];  // [5120]
    const float* thlclc = (const float*)d_in[3];  // [5120, 5120]
    float* out = (float*)d_out;                   // [1024]

    // ws layout: Tt (bf16 5120x5120 = 52.4 MB) | Xb (bf16 1024x5120 = 10.5 MB)
    unsigned short* Tt = (unsigned short*)d_ws;
    unsigned short* Xb = (unsigned short*)((char*)d_ws + (size_t)LCN * LCN * 2);

    k_theta<<<dim3(LCN / 64, LCN / 64), 256, 0, stream>>>(thlclc, Tt);
    k_init<<<dim3(BN), 256, 0, stream>>>(x, th0, thlc, out, Xb);

    int tot = 0;
    for (int t = 0; t < 40; ++t) {
        const int lmax = (128 * t + 127) / CN;
        tot += (CN * lmax + 511) / 512;
    }
    const int groups = (tot + 7) / 8;             // 28
    k_quad<<<dim3(groups * 64), 256, 0, stream>>>(Xb, Tt, out, tot);
}

// Round 3
// 231.967 us; speedup vs baseline: 1.1972x; 1.0076x over previous
//
#include <hip/hip_runtime.h>
#include <hip/hip_bf16.h>
#include <cstdint>
#include <cstddef>

// Problem constants (L=256, C=20, LC=5120, BATCH=1024)
#define LCN 5120
#define BN  1024
#define CN  20
#define TP  65   // LDS transpose tile pad (odd -> conflict-light both phases)

typedef __attribute__((ext_vector_type(4))) float  floatx4;
typedef __attribute__((ext_vector_type(8))) short  shortx8;
typedef __attribute__((ext_vector_type(4))) unsigned short ushortx4;
typedef __attribute__((ext_vector_type(8))) unsigned short ushortx8;

static __device__ __forceinline__ unsigned short f2bf(float f) {
    __hip_bfloat16 h = __float2bfloat16(f);
    return *reinterpret_cast<unsigned short*>(&h);
}

static __device__ __forceinline__ void gload_lds16(const void* g, void* l) {
    __builtin_amdgcn_global_load_lds(
        (const __attribute__((address_space(1))) void*)g,
        (__attribute__((address_space(3))) void*)l,
        16, 0, 0);
}

// ---------------------------------------------------------------------------
// Pass 1a: masked bf16 transpose through LDS.
//   Tt[i*5120 + j] = bf16(theta[j*5120 + i]) if l(i) > l(j) else 0
// 64x64 tiles; reads coalesced (float4), writes coalesced (ushortx8).
// Blocks beyond the chunk boundary k_quad reads are pruned.
// ---------------------------------------------------------------------------
__global__ __launch_bounds__(256) void k_theta(const float* __restrict__ th,
                                               unsigned short* __restrict__ Tt) {
    const int i0 = blockIdx.x * 64;
    const int j0 = blockIdx.y * 64;
    const int lmax = (128 * (i0 / 128) + 127) / CN;
    const int ch   = (CN * lmax + 511) / 512;
    if (j0 >= ch * 512) return;

    __shared__ unsigned short Ts[64 * TP];   // [j_local][i_local]
    const int t = threadIdx.x;
    const int c = t & 15, r = t >> 4;        // read: 16 lanes x 16B per j-row
#pragma unroll
    for (int rr = 0; rr < 4; ++rr) {
        const int j  = j0 + rr * 16 + r;
        const int lj = j / CN;
        const floatx4 v = *reinterpret_cast<const floatx4*>(th + (size_t)j * LCN + i0 + c * 4);
#pragma unroll
        for (int e = 0; e < 4; ++e) {
            const int li = (i0 + c * 4 + e) / CN;
            Ts[(rr * 16 + r) * TP + c * 4 + e] = (li > lj) ? f2bf(v[e]) : (unsigned short)0;
        }
    }
    __syncthreads();
    const int c2 = t & 7, r2 = t >> 3;       // write: 8 lanes x 16B per i-row
#pragma unroll
    for (int ww = 0; ww < 2; ++ww) {
        const int il = ww * 32 + r2;
        ushortx8 o;
#pragma unroll
        for (int e = 0; e < 8; ++e) o[e] = Ts[(c2 * 8 + e) * TP + il];
        *reinterpret_cast<ushortx8*>(Tt + (size_t)(i0 + il) * LCN + j0 + c2 * 8) = o;
    }
}

// ---------------------------------------------------------------------------
// Pass 1b: fused  out[b] = theta_0 + sum_i theta_lc[i]*x[b,i]  (fp32, exact)
//          and    Xb[b,i] = bf16(x[b,i])
// ---------------------------------------------------------------------------
__global__ __launch_bounds__(256) void k_init(const float* __restrict__ x,
                                              const float* __restrict__ th0,
                                              const float* __restrict__ thlc,
                                              float* __restrict__ out,
                                              unsigned short* __restrict__ Xb) {
    const int b = blockIdx.x;
    const int tid = threadIdx.x;
    const floatx4* xr = reinterpret_cast<const floatx4*>(x + (size_t)b * LCN);
    const floatx4* tr = reinterpret_cast<const floatx4*>(thlc);
    ushortx4* xw = reinterpret_cast<ushortx4*>(Xb + (size_t)b * LCN);
    float s = 0.0f;
    for (int k = tid; k < LCN / 4; k += 256) {
        const floatx4 a = xr[k], t2 = tr[k];
        s += a[0] * t2[0] + a[1] * t2[1] + a[2] * t2[2] + a[3] * t2[3];
        ushortx4 o;
#pragma unroll
        for (int e = 0; e < 4; ++e) o[e] = f2bf(a[e]);
        xw[k] = o;
    }
#pragma unroll
    for (int off = 32; off > 0; off >>= 1) s += __shfl_down(s, off, 64);
    __shared__ float ws4[4];
    if ((tid & 63) == 0) ws4[tid >> 6] = s;
    __syncthreads();
    if (tid == 0) out[b] = th0[0] + ws4[0] + ws4[1] + ws4[2] + ws4[3];
}

// ---------------------------------------------------------------------------
// Pass 2: masked-GEMM + fused dot-reduce (m97 structure, 128x128 tile, BK=32).
// XCD-pinned 1-D grid decode (id%8 round-robin assumption).
// LDS SEGMENT SWIZZLE: global 16B segment g of row r is stored at LDS slot
// (g + (r>>1)) & 3. Fragment readers use seg = (kq + (row>>1)) & 3. This
// breaks the 8-way bank conflict of the naive [row][32] layout (row stride
// 64B = 16 banks -> even rows all hit banks 0-3) down to 2-way (free).
// ---------------------------------------------------------------------------
__global__ __launch_bounds__(256) void k_quad(
    const unsigned short* __restrict__ Xb,   // [1024][5120] bf16
    const unsigned short* __restrict__ Tt,   // [5120][5120] bf16, row i over j
    float*                __restrict__ out,  // [1024]
    const int tot)                           // total chunk count (220)
{
    const int bid  = blockIdx.x;
    const int xcd  = bid & 7;
    const int slot = bid >> 3;
    const int m    = slot & 7;
    const int g    = slot >> 3;
    int q = g * 8 + xcd;
    if (q >= tot) return;

    __shared__ unsigned short As[128 * 32];   // A tile: [row b][4 swizzled 16B segs]
    __shared__ unsigned short Bs[128 * 32];   // B tile: [row i][4 swizzled 16B segs]
    __shared__ float partial[128];

    const int tid  = threadIdx.x;
    const int lane = tid & 63;
    const int w    = tid >> 6;        // wave 0..3
    const int wm   = w & 1;           // M half
    const int wn   = w >> 1;          // N half
    const int lrow = lane & 15;
    const int kq   = lane >> 4;       // 0..3

    // map chunk ordinal q -> (n, c)
    int n = 0, c = 0;
    for (int t = 0; t < 40; ++t) {
        const int lmax = (128 * t + 127) / CN;
        const int chn  = (CN * lmax + 511) / 512;
        if (q < chn) { n = t; c = q; break; }
        q -= chn;
    }
    const int b0 = m * 128;
    const int n0 = n * 128;
    const int k0 = c * 512;

    if (tid < 128) partial[tid] = 0.0f;

    floatx4 acc[4][4];
#pragma unroll
    for (int mt = 0; mt < 4; ++mt)
#pragma unroll
        for (int nt = 0; nt < 4; ++nt) acc[mt][nt] = (floatx4)0.0f;

    // precompute swizzled fragment offsets (ushort units)
    int aoff[4], boff[4];
#pragma unroll
    for (int mt = 0; mt < 4; ++mt) {
        const int row = wm * 64 + mt * 16 + lrow;
        aoff[mt] = row * 32 + (((kq + (row >> 1)) & 3) << 3);
    }
#pragma unroll
    for (int nt = 0; nt < 4; ++nt) {
        const int row = wn * 64 + nt * 16 + lrow;
        boff[nt] = row * 32 + (((kq + (row >> 1)) & 3) << 3);
    }

    for (int kk = 0; kk < 16; ++kk) {
        const int kc = k0 + kk * 32;
        // stage A/B: 512 x 16B segs per tile; LDS slot s=(row,seg) holds
        // global segment ((seg - (row>>1)) & 3) of that row.
#pragma unroll
        for (int t = 0; t < 2; ++t) {
            const int s    = t * 256 + tid;
            const int row  = s >> 2;
            const int gseg = ((s & 3) - (row >> 1)) & 3;
            char* la = (char*)As + (size_t)(t * 256 + w * 64) * 16;  // wave-uniform
            char* lb = (char*)Bs + (size_t)(t * 256 + w * 64) * 16;
            gload_lds16(Xb + (size_t)(b0 + row) * LCN + kc + gseg * 8, la);
            gload_lds16(Tt + (size_t)(n0 + row) * LCN + kc + gseg * 8, lb);
        }
        __syncthreads();

        shortx8 af[4], bfr[4];
#pragma unroll
        for (int mt = 0; mt < 4; ++mt)
            af[mt] = *reinterpret_cast<const shortx8*>(As + aoff[mt]);
#pragma unroll
        for (int nt = 0; nt < 4; ++nt)
            bfr[nt] = *reinterpret_cast<const shortx8*>(Bs + boff[nt]);
#pragma unroll
        for (int mt = 0; mt < 4; ++mt)
#pragma unroll
            for (int nt = 0; nt < 4; ++nt)
                acc[mt][nt] = __builtin_amdgcn_mfma_f32_16x16x32_bf16(af[mt], bfr[nt], acc[mt][nt], 0, 0, 0);
        __syncthreads();
    }

    // Epilogue: C/D layout col = lane&15 (i), row = (lane>>4)*4 + reg (b)
#pragma unroll
    for (int mt = 0; mt < 4; ++mt) {
#pragma unroll
        for (int r = 0; r < 4; ++r) {
            const int b = b0 + wm * 64 + mt * 16 + kq * 4 + r;
            float s = 0.0f;
#pragma unroll
            for (int nt = 0; nt < 4; ++nt) {
                const int i = n0 + wn * 64 + nt * 16 + lrow;
                const __hip_bfloat16 hv = *reinterpret_cast<const __hip_bfloat16*>(&Xb[(size_t)b * LCN + i]);
                s += acc[mt][nt][r] * __bfloat162float(hv);
            }
            s += __shfl_xor(s, 1, 64);
            s += __shfl_xor(s, 2, 64);
            s += __shfl_xor(s, 4, 64);
            s += __shfl_xor(s, 8, 64);
            if (lrow == 0) atomicAdd(&partial[b - b0], s);
        }
    }
    __syncthreads();
    if (tid < 128) atomicAdd(&out[b0 + tid], partial[tid]);
}

// ---------------------------------------------------------------------------
extern "C" void kernel_launch(void* const* d_in, const int* in_sizes, int n_in,
                              void* d_out, int out_size, void* d_ws, size_t ws_size,
                              hipStream_t stream) {
    const float* x      = (const float*)d_in[0];  // [1024, 5120]
    const float* th0    = (const float*)d_in[1];  // [1]
    const float* thlc   = (const float*)d_in[2];  // [5120]
    const float* thlclc = (const float*)d_in[3];  // [5120, 5120]
    float* out = (float*)d_out;                   // [1024]

    // ws layout: Tt (bf16 5120x5120 = 52.4 MB) | Xb (bf16 1024x5120 = 10.5 MB)
    unsigned short* Tt = (unsigned short*)d_ws;
    unsigned short* Xb = (unsigned short*)((char*)d_ws + (size_t)LCN * LCN * 2);

    k_theta<<<dim3(LCN / 64, LCN / 64), 256, 0, stream>>>(thlclc, Tt);
    k_init<<<dim3(BN), 256, 0, stream>>>(x, th0, thlc, out, Xb);

    int tot = 0;
    for (int t = 0; t < 40; ++t) {
        const int lmax = (128 * t + 127) / CN;
        tot += (CN * lmax + 511) / 512;
    }
    const int groups = (tot + 7) / 8;             // 28
    k_quad<<<dim3(groups * 64), 256, 0, stream>>>(Xb, Tt, out, tot);
}